// Round 1
// baseline (789.802 us; speedup 1.0000x reference)
//
#include <hip/hip_runtime.h>

#define QN 512
#define TN 256
#define KPL 8              // columns per lane = QN / 64
#define INFV 1000000000.0f // matches jnp.float32(1e9)

// ---------------------------------------------------------------------------
// Cost matrix: C[b][q][t] = |out[b][q].x - tgt[b][t].x| + |out[b][q].y - tgt[b][t].y|
// grid (512, 8), block 256 (t contiguous -> coalesced 4B writes)
// ---------------------------------------------------------------------------
__global__ __launch_bounds__(256) void cost_kernel(const float2* __restrict__ outputs,
                                                   const float2* __restrict__ targets,
                                                   float* __restrict__ C) {
    const int t = threadIdx.x;   // 0..255
    const int q = blockIdx.x;    // 0..511
    const int b = blockIdx.y;    // 0..7
    float2 o = outputs[b * QN + q];   // uniform across block -> scalar load
    float2 g = targets[b * TN + t];   // coalesced float2
    C[(size_t)(b * QN + q) * TN + t] = fabsf(o.x - g.x) + fabsf(o.y - g.y);
}

// ---------------------------------------------------------------------------
// Jonker-Volgenant Hungarian, one wave (64 lanes) per batch, 8 cols/lane.
// Bit-exact replica of the JAX reference's FP trajectory:
//   cur = (cost - u[i0]) - v[j];  first-min argmin;  per-iter +=/-= delta.
// ---------------------------------------------------------------------------
__global__ __launch_bounds__(64) void hung_kernel(const float2* __restrict__ outputs,
                                                  const float2* __restrict__ targets,
                                                  float* __restrict__ out_row,
                                                  float* __restrict__ out_col) {
    const int b = blockIdx.x;
    const int l = threadIdx.x;   // lane 0..63

    __shared__ float s_u[TN];
    __shared__ float s_tx[TN], s_ty[TN];
    __shared__ int   s_p[QN + 1];
    __shared__ int   s_way[QN];

    // stage targets, init duals u
    for (int k = 0; k < TN / 64; ++k) {
        int t = l + 64 * k;
        float2 g = targets[b * TN + t];
        s_tx[t] = g.x; s_ty[t] = g.y; s_u[t] = 0.0f;
    }

    // per-lane column state: column j = l + 64*k  (k-major => ascending j groups)
    float ox[KPL], oy[KPL], v[KPL], minv[KPL];
    for (int k = 0; k < KPL; ++k) {
        int q = l + 64 * k;
        float2 o = outputs[b * QN + q];   // coalesced float2
        ox[k] = o.x; oy[k] = o.y;
        v[k] = 0.0f;
        s_p[q] = -1;
    }
    if (l == 0) s_p[QN] = -1;
    __syncthreads();

    for (int i = 0; i < TN; ++i) {
        if (l == 0) s_p[QN] = i;
        for (int k = 0; k < KPL; ++k) minv[k] = INFV;
        unsigned used = 0u;   // bit k => column l + 64*k is used
        int j0 = QN;          // uniform across lanes
        __syncthreads();

        while (true) {
            int i0 = s_p[j0];                      // uniform broadcast read
            if (j0 < QN && (j0 & 63) == l) used |= 1u << (j0 >> 6);

            float tx = s_tx[i0], ty = s_ty[i0], ui0 = s_u[i0];

            // per-lane scan: update minv/way, collect lane-local first-min of masked
            float bestv = INFV; int bestj = QN;
            #pragma unroll
            for (int k = 0; k < KPL; ++k) {
                int q = l + 64 * k;
                float cost = fabsf(ox[k] - tx) + fabsf(oy[k] - ty);
                float cur  = (cost - ui0) - v[k];
                bool us = (used >> k) & 1u;
                if (!us && cur < minv[k]) { minv[k] = cur; s_way[q] = j0; }
                float masked = us ? INFV : minv[k];
                // ascending k => ascending j, so strict < keeps smallest j on ties
                if (masked < bestv) { bestv = masked; bestj = q; }
            }

            // wave-wide lexicographic (value, index) min -> first-min semantics
            #pragma unroll
            for (int off = 1; off < 64; off <<= 1) {
                float ovv = __shfl_xor(bestv, off);
                int   ojj = __shfl_xor(bestj, off);
                if (ovv < bestv || (ovv == bestv && ojj < bestj)) { bestv = ovv; bestj = ojj; }
            }
            const int   j1    = bestj;
            const float delta = bestv;

            // dual updates (exact reference order: one +=/-= per iteration)
            #pragma unroll
            for (int k = 0; k < KPL; ++k) {
                int q = l + 64 * k;
                if ((used >> k) & 1u) {
                    s_u[s_p[q]] += delta;   // distinct rows, no conflict
                    v[k] -= delta;
                } else {
                    minv[k] -= delta;
                }
            }
            if (l == 0) s_u[i] += delta;    // virtual column QN (used from iter 1)

            j0 = j1;
            __syncthreads();                 // order s_u writes before next reads
            if (s_p[j0] == -1) break;        // uniform
        }

        // augmenting path (serial chain, short)
        if (l == 0) {
            int jj = j0;
            while (jj != QN) { int jn = s_way[jj]; s_p[jj] = s_p[jn]; jj = jn; }
        }
        __syncthreads();
    }

    // Emit matched pairs sorted by query index.
    // Ranks: count of valid columns with smaller j (k-major groups ascending).
    int rank_base = 0;
    for (int k = 0; k < KPL; ++k) {
        int q = l + 64 * k;
        int pq = s_p[q];
        bool valid = pq >= 0;
        unsigned long long m = __ballot(valid);
        int below = __popcll(m & ((1ull << l) - 1ull));
        if (valid) {
            int r = rank_base + below;
            out_row[b * TN + r] = (float)q;
            out_col[b * TN + r] = (float)pq;
        }
        rank_base += __popcll(m);
    }
}

extern "C" void kernel_launch(void* const* d_in, const int* in_sizes, int n_in,
                              void* d_out, int out_size, void* d_ws, size_t ws_size,
                              hipStream_t stream) {
    const float2* outputs = (const float2*)d_in[0];   // [8,512,2] f32
    const float2* targets = (const float2*)d_in[1];   // [8,256,2] f32
    float* out = (float*)d_out;
    float* out_row = out;                 // [8,256] as float
    float* out_col = out + 8 * TN;        // [8,256] as float
    float* C       = out + 2 * 8 * TN;    // [8,512,256] f32

    dim3 gridC(QN, 8);
    cost_kernel<<<gridC, TN, 0, stream>>>(outputs, targets, C);
    hung_kernel<<<8, 64, 0, stream>>>(outputs, targets, out_row, out_col);
}

// Round 2
// 458.397 us; speedup vs baseline: 1.7230x; 1.7230x over previous
//
#include <hip/hip_runtime.h>

#define QN 512
#define TN 256
#define KPL 8              // columns per lane = QN / 64
#define RPL 4              // rows per lane    = TN / 64
#define INFV 1000000000.0f // matches jnp.float32(1e9)

// ---------------------------------------------------------------------------
// Cost matrix: C[b][q][t] = |out[b][q].x - tgt[b][t].x| + |out[b][q].y - tgt[b][t].y|
// ---------------------------------------------------------------------------
__global__ __launch_bounds__(256) void cost_kernel(const float2* __restrict__ outputs,
                                                   const float2* __restrict__ targets,
                                                   float* __restrict__ C) {
    const int t = threadIdx.x;
    const int q = blockIdx.x;
    const int b = blockIdx.y;
    float2 o = outputs[b * QN + q];
    float2 g = targets[b * TN + t];
    C[(size_t)(b * QN + q) * TN + t] = fabsf(o.x - g.x) + fabsf(o.y - g.y);
}

// lexicographic (value, index) min-combine with a DPP-rotated partner.
// row_ror codes: 0x120 | n  (rotate within 16-lane rows). 4 steps (1,2,4,8)
// leave every lane holding its row's lex-min.
template <int CTRL>
__device__ __forceinline__ void lexmin_dpp(float& bv, int& bj) {
    int ovi = __builtin_amdgcn_update_dpp(0, __builtin_bit_cast(int, bv), CTRL, 0xF, 0xF, true);
    int oji = __builtin_amdgcn_update_dpp(0, bj, CTRL, 0xF, 0xF, true);
    float ov = __builtin_bit_cast(float, ovi);
    if (ov < bv || (ov == bv && oji < bj)) { bv = ov; bj = oji; }
}

__device__ __forceinline__ float readlane_f(float v, int lane) {
    return __builtin_bit_cast(float, __builtin_amdgcn_readlane(__builtin_bit_cast(int, v), lane));
}

// ---------------------------------------------------------------------------
// Jonker-Volgenant Hungarian, one wave per batch, ZERO LDS.
// Columns lane-distributed (8 slots/lane), rows lane-distributed (4 slots/lane).
// Uniform-index lookups = unrolled slot-select + v_readlane (VALU latency).
// Bit-exact replica of the JAX reference's FP trajectory.
// ---------------------------------------------------------------------------
__global__ __launch_bounds__(64) void hung_kernel(const float2* __restrict__ outputs,
                                                  const float2* __restrict__ targets,
                                                  float* __restrict__ out_row,
                                                  float* __restrict__ out_col) {
    const int b = blockIdx.x;
    const int l = threadIdx.x;   // lane 0..63

    // row-distributed state: row r = l + 64*s
    float tx_r[RPL], ty_r[RPL], u_r[RPL];
    #pragma unroll
    for (int s = 0; s < RPL; ++s) {
        float2 g = targets[b * TN + l + 64 * s];
        tx_r[s] = g.x; ty_r[s] = g.y; u_r[s] = 0.0f;
    }

    // column-distributed state: col j = l + 64*k
    float ox[KPL], oy[KPL], v[KPL], minv[KPL], usedf[KPL];
    int p_r[KPL], way_r[KPL];
    #pragma unroll
    for (int k = 0; k < KPL; ++k) {
        float2 o = outputs[b * QN + l + 64 * k];
        ox[k] = o.x; oy[k] = o.y; v[k] = 0.0f;
        p_r[k] = -1; way_r[k] = QN;
    }

    for (int i = 0; i < TN; ++i) {
        #pragma unroll
        for (int k = 0; k < KPL; ++k) { minv[k] = INFV; usedf[k] = 0.0f; }
        unsigned rmask = 0u;   // this-Dijkstra used-row bits (slots)

        int i0 = i;            // row reached via current column (p[QN] = i)
        int j0 = QN;           // current column (QN = virtual start)

        for (;;) {
            // mark column j0 used (owner lane), matching reference body start
            if (j0 < QN) {
                const int cs = j0 >> 6;
                const bool own = (l == (j0 & 63));
                #pragma unroll
                for (int s = 0; s < KPL; ++s)
                    if (cs == s && own) usedf[s] = INFV;
            }
            // mark row i0 used (owner lane)
            {
                const int rs = i0 >> 6;
                const bool own = (l == (i0 & 63));
                #pragma unroll
                for (int s = 0; s < RPL; ++s)
                    if (rs == s && own) rmask |= 1u << s;
            }

            // fetch row data u[i0], tx[i0], ty[i0] as uniforms (select + readlane)
            const int rslot = i0 >> 6, rlane = i0 & 63;
            float usel = u_r[0], txsel = tx_r[0], tysel = ty_r[0];
            #pragma unroll
            for (int s = 1; s < RPL; ++s) {
                usel  = (rslot == s) ? u_r[s]  : usel;
                txsel = (rslot == s) ? tx_r[s] : txsel;
                tysel = (rslot == s) ? ty_r[s] : tysel;
            }
            const float ui0 = readlane_f(usel, rlane);
            const float txv = readlane_f(txsel, rlane);
            const float tyv = readlane_f(tysel, rlane);

            // scan: update minv/way; collect lane-local first-min of masked
            float bestv = INFV; int bestj = QN;
            #pragma unroll
            for (int k = 0; k < KPL; ++k) {
                const float cost = fabsf(ox[k] - txv) + fabsf(oy[k] - tyv);
                const float cur  = (cost - ui0) - v[k];
                const bool  us   = usedf[k] > 0.0f;
                const float gate = us ? -INFV : minv[k];   // used => never better
                const bool  better = cur < gate;
                minv[k]  = better ? cur : minv[k];
                way_r[k] = better ? j0  : way_r[k];
                // masked: unused -> minv (exact); used -> ~1e9, can never win
                const float masked = minv[k] + usedf[k];
                const int j = l + 64 * k;
                if (masked < bestv) { bestv = masked; bestj = j; }   // ascending j per lane
            }

            // wave lex-min: 4 DPP row_ror steps, then 4-row readlane combine
            lexmin_dpp<0x121>(bestv, bestj);
            lexmin_dpp<0x122>(bestv, bestj);
            lexmin_dpp<0x124>(bestv, bestj);
            lexmin_dpp<0x128>(bestv, bestj);
            float dv; int dj;
            {
                const float v0 = readlane_f(bestv, 0),  v1 = readlane_f(bestv, 16);
                const float v2 = readlane_f(bestv, 32), v3 = readlane_f(bestv, 48);
                const int   a0 = __builtin_amdgcn_readlane(bestj, 0);
                const int   a1 = __builtin_amdgcn_readlane(bestj, 16);
                const int   a2 = __builtin_amdgcn_readlane(bestj, 32);
                const int   a3 = __builtin_amdgcn_readlane(bestj, 48);
                dv = v0; dj = a0;
                if (v1 < dv || (v1 == dv && a1 < dj)) { dv = v1; dj = a1; }
                if (v2 < dv || (v2 == dv && a2 < dj)) { dv = v2; dj = a2; }
                if (v3 < dv || (v3 == dv && a3 < dj)) { dv = v3; dj = a3; }
            }
            const float delta = dv;
            const int   j1    = dj;

            // dual updates: one add/sub per element, exact reference order
            #pragma unroll
            for (int s = 0; s < RPL; ++s)
                u_r[s] = ((rmask >> s) & 1u) ? u_r[s] + delta : u_r[s];
            #pragma unroll
            for (int k = 0; k < KPL; ++k) {
                const bool us = usedf[k] > 0.0f;
                v[k]    = us ? v[k] - delta : v[k];
                minv[k] = us ? minv[k]      : minv[k] - delta;
            }

            // i0 = p[j1]; free column -> done
            const int cslot = j1 >> 6;
            int psel = p_r[0];
            #pragma unroll
            for (int s = 1; s < KPL; ++s) psel = (cslot == s) ? p_r[s] : psel;
            const int pi = __builtin_amdgcn_readlane(psel, j1 & 63);
            j0 = j1;
            if (pi == -1) break;
            i0 = pi;
        }

        // augmenting path: p[jj] = p[way[jj]] along the chain (register writes)
        int jj = j0;
        for (;;) {
            const int ws = jj >> 6, wl = jj & 63;
            int wsel = way_r[0];
            #pragma unroll
            for (int s = 1; s < KPL; ++s) wsel = (ws == s) ? way_r[s] : wsel;
            const int jn = __builtin_amdgcn_readlane(wsel, wl);
            int pn;
            if (jn == QN) pn = i;
            else {
                const int ps = jn >> 6;
                int psel = p_r[0];
                #pragma unroll
                for (int s = 1; s < KPL; ++s) psel = (ps == s) ? p_r[s] : psel;
                pn = __builtin_amdgcn_readlane(psel, jn & 63);
            }
            {
                const bool own = (l == wl);
                #pragma unroll
                for (int s = 0; s < KPL; ++s)
                    if (ws == s && own) p_r[s] = pn;
            }
            if (jn == QN) break;
            jj = jn;
        }
    }

    // emit matched pairs sorted by query index (ballot-rank, k-major ascending j)
    int rank_base = 0;
    #pragma unroll
    for (int k = 0; k < KPL; ++k) {
        const int pq = p_r[k];
        const bool valid = pq >= 0;
        unsigned long long m = __ballot(valid);
        int below = __popcll(m & ((1ull << l) - 1ull));
        if (valid) {
            int r = rank_base + below;
            out_row[b * TN + r] = (float)(l + 64 * k);
            out_col[b * TN + r] = (float)pq;
        }
        rank_base += __popcll(m);
    }
}

extern "C" void kernel_launch(void* const* d_in, const int* in_sizes, int n_in,
                              void* d_out, int out_size, void* d_ws, size_t ws_size,
                              hipStream_t stream) {
    const float2* outputs = (const float2*)d_in[0];   // [8,512,2] f32
    const float2* targets = (const float2*)d_in[1];   // [8,256,2] f32
    float* out = (float*)d_out;
    float* out_row = out;                 // [8,256] as float
    float* out_col = out + 8 * TN;        // [8,256] as float
    float* C       = out + 2 * 8 * TN;    // [8,512,256] f32

    dim3 gridC(QN, 8);
    cost_kernel<<<gridC, TN, 0, stream>>>(outputs, targets, C);
    hung_kernel<<<8, 64, 0, stream>>>(outputs, targets, out_row, out_col);
}